// Round 7
// baseline (89.929 us; speedup 1.0000x reference)
//
#include <hip/hip_runtime.h>
#include <math.h>

#define HW 16384
#define NC 64
#define NB 16

// Panel format (both tensors): per (b, pb) panel of 64 k-columns:
//   8 KB = [c=0..63][64 k] bf16, ushort index  c*64 + ((kk>>3)^(c&7))*8 + (kk&7)
// (identical to R2's LDS tile layout, which measured 0 bank conflicts).
// ev panels live in d_out[0, 32MB), et panels in d_out[32MB, 64MB).
// ws layout (floats):
//   [0,1024) S_v   [1024,2048) S_t   [2048,3072) U_t   [3072,4096) gw
//   [4096, 4096+npart*65536) J_raw partial copies

typedef __attribute__((ext_vector_type(8))) short bf16x8;
typedef __attribute__((ext_vector_type(4))) float f32x4;

__device__ inline unsigned short f2bf(float x) {
  union { float f; unsigned u; } v; v.f = x;
  unsigned r = v.u + 0x7FFFu + ((v.u >> 16) & 1u);   // RNE; exp>0 so no NaN
  return (unsigned short)(r >> 16);
}

__device__ inline float wave_reduce_sum(float v) {
#pragma unroll
  for (int o = 32; o > 0; o >>= 1) v += __shfl_down(v, o, 64);
  return v;
}

__device__ inline int lds_off(int r, int ko) {       // ushort units
  return r * 64 + ((ko ^ (r & 7)) << 3);
}

#if __has_builtin(__builtin_amdgcn_global_load_lds)
__device__ inline void gload16(const float* g, float* l) {
  __builtin_amdgcn_global_load_lds(
      (const __attribute__((address_space(1))) void*)g,
      (__attribute__((address_space(3))) void*)l, 16, 0, 0);
}
#else
__device__ inline void gload16(const float* g, float* l) {
  *(f32x4*)(l + (threadIdx.x & 63) * 4) = *(const f32x4*)g;
}
#endif

// ---------------- pass 1: contiguous-streaming transform + pack + stats ----
__global__ __launch_bounds__(256) void transform_pack(const float* __restrict__ vis,
                                                      const float* __restrict__ text,
                                                      ushort* __restrict__ ev,
                                                      ushort* __restrict__ et,
                                                      float* __restrict__ ws) {
  const int bid = blockIdx.x;               // 2048 = b(16) * c(64) * h(2)
  const int h = bid & 1, c = (bid >> 1) & 63, b = bid >> 7;
  const int t = threadIdx.x;
  const int w = t >> 6, l = t & 63;

  const float* vrow = vis  + ((size_t)b * NC + c) * HW + h * 8192;
  const float* trow = text + ((size_t)b * NC + c) * HW + h * 8192;

  // per-thread constant within-panel offset: k = i*1024 + t*4, kk = k&63 = (4t)&63
  const int kk = (4 * t) & 63;
  const int off = c * 64 + (((kk >> 3) ^ (c & 7)) * 8) + (kk & 7);
  const int pb0 = b * 256 + h * 128 + (t >> 4);     // + i*16 per iter

  float sv = 0.f, st = 0.f, ut = 0.f;
#pragma unroll
  for (int i = 0; i < 8; ++i) {
    f32x4 v = *(const f32x4*)(vrow + i * 1024 + t * 4);
    f32x4 x = *(const f32x4*)(trow + i * 1024 + t * 4);
    float e0 = __expf(v[0]), e1 = __expf(v[1]), e2 = __expf(v[2]), e3 = __expf(v[3]);
    float g0 = __expf(x[0]), g1 = __expf(x[1]), g2 = __expf(x[2]), g3 = __expf(x[3]);
    sv += (e0 + e1) + (e2 + e3);
    st += (g0 + g1) + (g2 + g3);
    ut += (g0 * x[0] + g1 * x[1]) + (g2 * x[2] + g3 * x[3]);
    ushort4 pv = make_ushort4(f2bf(e0), f2bf(e1), f2bf(e2), f2bf(e3));
    ushort4 pt = make_ushort4(f2bf(g0), f2bf(g1), f2bf(g2), f2bf(g3));
    size_t pbase = (size_t)(pb0 + i * 16) * 4096;
    *reinterpret_cast<ushort4*>(ev + pbase + off) = pv;
    *reinterpret_cast<ushort4*>(et + pbase + off) = pt;
  }

  sv = wave_reduce_sum(sv);
  st = wave_reduce_sum(st);
  ut = wave_reduce_sum(ut);
  __shared__ float sred[12];
  if (l == 0) { sred[w] = sv; sred[4 + w] = st; sred[8 + w] = ut; }
  __syncthreads();
  if (t == 0) {
    atomicAdd(&ws[        b * 64 + c], (sred[0] + sred[1]) + (sred[2] + sred[3]));
    atomicAdd(&ws[1024 + b * 64 + c], (sred[4] + sred[5]) + (sred[6] + sred[7]));
    atomicAdd(&ws[2048 + b * 64 + c], (sred[8] + sred[9]) + (sred[10] + sred[11]));
  }
}

// ---------------- pass 2: flat-panel MFMA GEMM (4-slot pipelined) -----------
// issue pair q (ev panel + et panel, 16 KB) into slot q&3; 4 instr per wave
#define PISSUE(q) do {                                                  \
    const float* s1_ = evb + (q) * 2048 + w * 256 + l * 4;              \
    const float* s2_ = etb + (q) * 2048 + w * 256 + l * 4;              \
    float* d_ = (float*)sl[(q) & 3] + w * 256;                          \
    gload16(s1_,        d_);                                            \
    gload16(s1_ + 1024, d_ + 1024);                                     \
    gload16(s2_,        d_ + 2048);                                     \
    gload16(s2_ + 1024, d_ + 3072);                                     \
  } while (0)

#define JSTEP(p, VMC, DO_ISSUE) do {                                    \
    asm volatile("s_waitcnt vmcnt(" VMC ")" ::: "memory");              \
    __builtin_amdgcn_sched_barrier(0);                                  \
    __builtin_amdgcn_s_barrier();                                       \
    DO_ISSUE;                                                           \
    const ushort* EVp = sl[(p) & 3];                                    \
    const ushort* ETp = EVp + 4096;                                     \
    bf16x8 af[4][2];                                                    \
    _Pragma("unroll") for (int fi = 0; fi < 4; ++fi) {                  \
      af[fi][0] = *(const bf16x8*)&EVp[lds_off(fi * 16 + m16, ks0)];    \
      af[fi][1] = *(const bf16x8*)&EVp[lds_off(fi * 16 + m16, ks0 + 4)];\
    }                                                                   \
    bf16x8 bf0 = *(const bf16x8*)&ETp[lds_off(w * 16 + m16, ks0)];      \
    bf16x8 bf1 = *(const bf16x8*)&ETp[lds_off(w * 16 + m16, ks0 + 4)];  \
    asm volatile("s_waitcnt lgkmcnt(0)" ::: "memory");                  \
    __builtin_amdgcn_sched_barrier(0);                                  \
    _Pragma("unroll") for (int fi = 0; fi < 4; ++fi) {                  \
      acc[fi] = __builtin_amdgcn_mfma_f32_16x16x32_bf16(af[fi][0], bf0, acc[fi], 0, 0, 0); \
      acc[fi] = __builtin_amdgcn_mfma_f32_16x16x32_bf16(af[fi][1], bf1, acc[fi], 0, 0, 0); \
    }                                                                   \
  } while (0)

__global__ __launch_bounds__(256) void jgemm(const ushort* __restrict__ ev,
                                             const ushort* __restrict__ et,
                                             float* __restrict__ ws, int jmask) {
  const int b = blockIdx.x >> 5, chunk = blockIdx.x & 31;   // 512 blocks
  const int t = threadIdx.x, w = t >> 6, l = t & 63;
  const int m16 = l & 15, ks0 = l >> 4;

  __shared__ ushort sl[4][8192];        // 4 slots x (ev panel | et panel)

  const float* evb = (const float*)(ev + ((size_t)b * 256 + chunk * 8) * 4096);
  const float* etb = (const float*)(et + ((size_t)b * 256 + chunk * 8) * 4096);

  f32x4 acc[4];
#pragma unroll
  for (int i = 0; i < 4; ++i) acc[i] = (f32x4){0.f, 0.f, 0.f, 0.f};

  // prologue: 3 pairs in flight (12 instr/wave)
  PISSUE(0); PISSUE(1); PISSUE(2);

  JSTEP(0, "8", PISSUE(3));
  JSTEP(1, "8", PISSUE(4));
  JSTEP(2, "8", PISSUE(5));
  JSTEP(3, "8", PISSUE(6));
  JSTEP(4, "8", PISSUE(7));
  JSTEP(5, "8", (void)0);
  JSTEP(6, "4", (void)0);
  JSTEP(7, "0", (void)0);

  // C/D layout: col = l&15, row = (l>>4)*4 + reg (verified R2/R4/R5)
  // wave w owns n in [16w, 16w+16) -> disjoint addresses across waves
  float* Jp = ws + 4096 + (size_t)((chunk & jmask) * NB + b) * 4096;
  const int q4 = (l >> 4) * 4;
#pragma unroll
  for (int fi = 0; fi < 4; ++fi)
#pragma unroll
    for (int r = 0; r < 4; ++r)
      atomicAdd(&Jp[(fi * 16 + q4 + r) * 64 + w * 16 + m16], acc[fi][r]);
}

// ---------------- pass 3: MI + guide weights -------------------------------
__global__ __launch_bounds__(256) void mi_gw_kernel(const float* __restrict__ ws,
                                                    float* __restrict__ gw,
                                                    int npart) {
  const int b = blockIdx.x, t = threadIdx.x;
  __shared__ float sSv[64], sSt[64];
  if (t < 64) sSv[t] = ws[b * 64 + t];
  else if (t < 128) sSt[t - 64] = ws[1024 + b * 64 + (t - 64)];
  __syncthreads();

  f32x4 jr0 = {0,0,0,0}, jr1 = {0,0,0,0}, jr2 = {0,0,0,0}, jr3 = {0,0,0,0};
  const float* base = ws + 4096 + (size_t)b * 4096 + t * 16;
  for (int p = 0; p < npart; ++p) {
    const f32x4* cp = (const f32x4*)(base + (size_t)p * (NB * 4096));
    jr0 += cp[0]; jr1 += cp[1]; jr2 += cp[2]; jr3 += cp[3];
  }

  const float HW2 = (float)HW * (float)HW;
  const float fv = HW2 / sSv[t >> 2];
  const int d0 = (t & 3) * 16;
  float part = 0.f;
#pragma unroll
  for (int j = 0; j < 16; ++j) {
    float jv = (j < 4) ? jr0[j] : (j < 8) ? jr1[j - 4] : (j < 12) ? jr2[j - 8] : jr3[j - 12];
    float q = jv * (fv / sSt[d0 + j]);
    part += q * __logf(q + 1e-9f);
  }
  part = wave_reduce_sum(part);
  __shared__ float sh[4];
  __shared__ float mi_sh;
  int wid = t >> 6, lane = t & 63;
  if (lane == 0) sh[wid] = part;
  __syncthreads();
  if (t == 0) mi_sh = ((sh[0] + sh[1]) + (sh[2] + sh[3])) / HW2;
  __syncthreads();
  if (t < 64) {
    float S = sSt[t];
    float U = ws[2048 + b * 64 + t];
    float ent = __logf(S) - U / S;               // text spatial entropy
    float z = 1.0f - ent + 0.5f * mi_sh;
    gw[b * 64 + t] = 1.0f / (1.0f + __expf(-z));
  }
}

// ---------------- pass 4: enhance ------------------------------------------
__global__ __launch_bounds__(256) void enhance_kernel(const float4* __restrict__ vis,
                                                      const float4* __restrict__ text,
                                                      const float* __restrict__ gw,
                                                      float4* __restrict__ out) {
  const size_t total4 = (size_t)NB * NC * HW / 4;   // 4194304
  for (size_t i = (size_t)blockIdx.x * 256 + threadIdx.x; i < total4;
       i += (size_t)gridDim.x * 256) {
    float4 v = vis[i];
    float4 t = text[i];
    float g = gw[i >> 12];              // 4096 float4 per (b,c) row
    out[i] = make_float4(v.x + g * t.x, v.y + g * t.y,
                         v.z + g * t.z, v.w + g * t.w);
  }
}

extern "C" void kernel_launch(void* const* d_in, const int* in_sizes, int n_in,
                              void* d_out, int out_size, void* d_ws, size_t ws_size,
                              hipStream_t stream) {
  const float* vis  = (const float*)d_in[0];
  const float* text = (const float*)d_in[1];
  float* out = (float*)d_out;
  float* ws  = (float*)d_ws;
  float* gw  = ws + 3072;

  // d_out doubles as the packed-panel scratch (fully overwritten by enhance)
  ushort* ev = (ushort*)d_out;
  ushort* et = ev + (size_t)16 * 256 * 4096;   // +32 MB

  size_t ws_floats = ws_size / sizeof(float);
  int npart = 1;
  if      (ws_floats >= 4096 + 4 * 65536) npart = 4;
  else if (ws_floats >= 4096 + 2 * 65536) npart = 2;

  hipMemsetAsync(ws, 0, (4096 + (size_t)npart * 65536) * sizeof(float), stream);

  transform_pack<<<2048, 256, 0, stream>>>(vis, text, ev, et, ws);
  jgemm<<<512, 256, 0, stream>>>(ev, et, ws, npart - 1);
  mi_gw_kernel<<<NB, 256, 0, stream>>>(ws, gw, npart);
  enhance_kernel<<<2048, 256, 0, stream>>>((const float4*)vis, (const float4*)text,
                                           gw, (float4*)out);
}